// Round 1
// 155.403 us; speedup vs baseline: 1.0079x; 1.0079x over previous
//
#include <hip/hip_runtime.h>

// Problem: B=8, S=2048, H=1024, D=64. fp32 in, fp32 out.
// out = softmax_causal(q k^T) / sqrt(H) @ v   (softmax FIRST, then /32)

typedef float     f32x4 __attribute__((ext_vector_type(4)));
typedef _Float16  f16x8 __attribute__((ext_vector_type(8)));
typedef _Float16  f16x4 __attribute__((ext_vector_type(4)));

// ---------------------------------------------------------------------------
// Kernel 1: pack W{q,k,v} into MFMA B-fragment order (f16) via LDS transpose.
// Frag f = (kstep*12 + nt)*64 + lane holds 8 f16:
//   element j = W[n = nt*16 + (lane&15)][k = kstep*32 + (lane>>4)*8 + j]
// Grid 48 = 3 W x 16 k-tiles of 64. Coalesced f32x4 reads; frag-ordered writes.
__global__ __launch_bounds__(256) void wt_prep(const float* __restrict__ Wq,
                                               const float* __restrict__ Wk,
                                               const float* __restrict__ Wv,
                                               _Float16* __restrict__ WtF) {
  const int w  = blockIdx.x >> 4;              // which W
  const int kt = blockIdx.x & 15;              // k-tile of 64
  const float* src = (w == 0) ? Wq : (w == 1 ? Wk : Wv);
  __shared__ _Float16 ls[64][72];              // [local k][n], padded
  const int t = threadIdx.x;
  {
    int rr = t >> 4;                           // 0..15
    int c4 = (t & 15) * 4;
    #pragma unroll
    for (int ri = 0; ri < 4; ++ri) {
      int k = rr + ri * 16;                    // local k 0..63
      f32x4 f = *(const f32x4*)&src[(size_t)(kt * 64 + k) * 64 + c4];
      #pragma unroll
      for (int j = 0; j < 4; ++j) ls[k][c4 + j] = (_Float16)f[j];
    }
  }
  __syncthreads();
  const int lane = t & 63, l16 = lane & 15, quad = lane >> 4;
  #pragma unroll
  for (int h = 0; h < 2; ++h) {
    int fid     = h * 4 + (t >> 6);            // 0..7
    int kstep_l = fid >> 2;                    // 0..1
    int ntl     = fid & 3;                     // 0..3
    int nt      = w * 4 + ntl;
    int kstep   = kt * 2 + kstep_l;
    f16x8 o;
    #pragma unroll
    for (int j = 0; j < 8; ++j) o[j] = ls[kstep_l * 32 + quad * 8 + j][ntl * 16 + l16];
    *(f16x8*)&WtF[((size_t)(kstep * 12 + nt) * 64 + lane) * 8] = o;
  }
}

// ---------------------------------------------------------------------------
// Kernel 2: QKV projection. Grid 512 (M-tile=32), 512 threads (8 waves),
// 2 blocks/CU -> 16 waves/CU. Whole 32x1024 x-tile staged ONCE into a 64KB
// XOR-swizzled LDS buffer (granule=8 f16; phys_g = g ^ (row&7) -> conflict-free
// staging writes AND A-frag ds_read_b128). Single barrier; then each wave
// independently streams 96 coalesced B-frag loads + 96 MFMAs.
// Wave split: mhalf = wave>>2 (16 rows), ngrp = wave&3 (3 n-tiles).
__global__ __launch_bounds__(512, 4) void qkv_gemm(const float* __restrict__ x,
                                                   const _Float16* __restrict__ WtF,
                                                   const float* __restrict__ bq,
                                                   const float* __restrict__ bk,
                                                   const float* __restrict__ bv,
                                                   _Float16* __restrict__ qo,
                                                   _Float16* __restrict__ ko,
                                                   _Float16* __restrict__ vt) {
  __shared__ _Float16 xs[32 * 1024];           // exactly 64 KB
  const int tid  = threadIdx.x;
  const int wave = tid >> 6, lane = tid & 63;
  const int l16  = lane & 15, quad = lane >> 4;
  const int mhalf = wave >> 2;                 // 0..1
  const int ngrp  = wave & 3;                  // 0..3
  const int m0    = blockIdx.x * 32;

  // --- stage x tile (fp32 -> f16), coalesced: 16-lane groups read 256B runs
  {
    int row   = tid >> 4;                      // 0..31
    int cbase = (tid & 15) * 4;
    const float* xrow = x + (size_t)(m0 + row) * 1024;
    int key = row & 7;
    #pragma unroll
    for (int j = 0; j < 16; ++j) {
      int col = cbase + j * 64;
      f32x4 f = *(const f32x4*)&xrow[col];
      f16x4 hh;
      #pragma unroll
      for (int e = 0; e < 4; ++e) hh[e] = (_Float16)f[e];
      int g   = col >> 3;                      // granule index 0..127
      int sub = col & 7;                       // 0 or 4
      *(f16x4*)&xs[(size_t)row * 1024 + (size_t)((g ^ key) << 3) + sub] = hh;
    }
  }
  __syncthreads();

  f32x4 acc0 = (f32x4){0.f,0.f,0.f,0.f};
  f32x4 acc1 = (f32x4){0.f,0.f,0.f,0.f};
  f32x4 acc2 = (f32x4){0.f,0.f,0.f,0.f};

  const int arow = mhalf * 16 + l16;
  const _Float16* abase = xs + (size_t)arow * 1024;
  const int akey = arow & 7;
  const _Float16* wbase = WtF + ((size_t)(ngrp * 3) * 64 + lane) * 8;

  #pragma unroll 4
  for (int kstep = 0; kstep < 32; ++kstep) {
    f16x8 a = *(const f16x8*)(abase + (((kstep * 4 + quad) ^ akey) << 3));
    const _Float16* wk = wbase + (size_t)kstep * (12 * 64 * 8);
    f16x8 b0 = *(const f16x8*)(wk);
    f16x8 b1 = *(const f16x8*)(wk + 512);
    f16x8 b2 = *(const f16x8*)(wk + 1024);
    acc0 = __builtin_amdgcn_mfma_f32_16x16x32_f16(a, b0, acc0, 0, 0, 0);
    acc1 = __builtin_amdgcn_mfma_f32_16x16x32_f16(a, b1, acc1, 0, 0, 0);
    acc2 = __builtin_amdgcn_mfma_f32_16x16x32_f16(a, b2, acc2, 0, 0, 0);
  }

  // --- epilogue: C/D col=lane&15, row=quad*4+r. Bias add, f16 write.
  f32x4 accs[3] = {acc0, acc1, acc2};
  #pragma unroll
  for (int i = 0; i < 3; ++i) {
    int nt  = ngrp * 3 + i;
    int col = nt * 16 + l16;
    float bias = (nt < 4) ? bq[col] : (nt < 8) ? bk[col - 64] : bv[col - 128];
    #pragma unroll
    for (int r = 0; r < 4; ++r) {
      int m = m0 + mhalf * 16 + quad * 4 + r;  // global row = b*2048+s
      _Float16 hv = (_Float16)(accs[i][r] + bias);
      if (nt < 4)      qo[(size_t)m * 64 + col] = hv;
      else if (nt < 8) ko[(size_t)m * 64 + (col - 64)] = hv;
      else {                                   // v stored transposed: vt[b][d][s]
        int b = m >> 11, s = m & 2047;
        vt[((size_t)b * 64 + (col - 128)) * 2048 + s] = hv;
      }
    }
  }
}

// ---------------------------------------------------------------------------
// Kernel 3: causal attention, flash-style online softmax, in-block split-KV.
// 1024 blocks x 256 threads (4 waves), per-wave private (m,l,o), LDS merge.
//
// SWAPPED-OPERAND layout (this round's change): scores computed as
// mfma(K, Q) -> S^T with col = q = l16, row = kv = quad*4+r. Row-stats
// (max/sum over kv) are per-lane register reductions + 2 shfl_xor across
// quads, replacing 32 shfl rounds/iteration with 4. m/l/alpha are per-lane
// scalars. P stored [q][kv] in LDS (b64 writes, b128 B-frag reads); PV is
// mfma(V^T, P^T) -> O with row = d, col = q. KV chunk doubled to 128/wave.
__global__ __launch_bounds__(256, 4) void attn(const _Float16* __restrict__ q,
                                               const _Float16* __restrict__ k,
                                               const _Float16* __restrict__ vt,
                                               float* __restrict__ out) {
  const int blk  = blockIdx.x;
  const int qt   = 127 - (blk >> 3);           // q-tile 0..127 (heavy first)
  const int b    = blk & 7;
  const int tid  = threadIdx.x;
  const int wave = tid >> 6, lane = tid & 63;
  const int l16  = lane & 15, quad = lane >> 4;
  const int q0   = qt * 16;

  __shared__ _Float16 P[4][16][136];           // per-wave P^T buffer [q][kv], padded
  __shared__ float    ob[4][16][68];           // per-wave partial O [q][d], 16B-aligned rows
  __shared__ float    mlb[4][2][16];           // per-wave (m, l) per q-row

  const _Float16* qb = q  + (size_t)b * 2048 * 64;
  const _Float16* kb = k  + (size_t)b * 2048 * 64;
  const _Float16* vb = vt + (size_t)b * 64 * 2048;

  f16x8 qf0 = *(const f16x8*)&qb[(q0 + l16) * 64 + quad * 8];
  f16x8 qf1 = *(const f16x8*)&qb[(q0 + l16) * 64 + 32 + quad * 8];

  f32x4 o[4];
  #pragma unroll
  for (int i = 0; i < 4; ++i) o[i] = (f32x4){0.f, 0.f, 0.f, 0.f};
  float m = -1e30f, l = 0.f;                   // per-lane: stats for q = q0+l16
  const float L2E = 1.44269504088896340736f;
  const int qrow  = q0 + l16;
  const int kvend = q0 + 16;                   // causal: skv <= sq <= q0+15

  for (int kv0 = wave * 128; kv0 < kvend; kv0 += 512) {
    f32x4 sc[8];                               // S^T: sc[t][r] = S[kv0+t*16+quad*4+r][q0+l16]
    #pragma unroll
    for (int t = 0; t < 8; ++t) {
      int kvc = kv0 + t * 16;
      f32x4 c;
      if (kvc < kvend) {
        c = (f32x4){0.f, 0.f, 0.f, 0.f};
        f16x8 kf0 = *(const f16x8*)&kb[(kvc + l16) * 64 + quad * 8];
        f16x8 kf1 = *(const f16x8*)&kb[(kvc + l16) * 64 + 32 + quad * 8];
        c = __builtin_amdgcn_mfma_f32_16x16x32_f16(kf0, qf0, c, 0, 0, 0);
        c = __builtin_amdgcn_mfma_f32_16x16x32_f16(kf1, qf1, c, 0, 0, 0);
        if (kvc + 15 > q0) {                   // causal mask, diagonal tiles only
          #pragma unroll
          for (int r = 0; r < 4; ++r)
            if (kvc + quad * 4 + r > qrow) c[r] = -1e30f;
        }
      } else {
        c = (f32x4){-1e30f, -1e30f, -1e30f, -1e30f};
      }
      sc[t] = c;
    }

    // row max: in-register over this lane's 32 kv values, then across quads
    float mx = -1e30f;
    #pragma unroll
    for (int t = 0; t < 8; ++t)
      mx = fmaxf(mx, fmaxf(fmaxf(sc[t][0], sc[t][1]), fmaxf(sc[t][2], sc[t][3])));
    mx = fmaxf(mx, __shfl_xor(mx, 16, 64));
    mx = fmaxf(mx, __shfl_xor(mx, 32, 64));
    float mnew  = fmaxf(m, mx);
    float alpha = exp2f((m - mnew) * L2E);
    m = mnew;

    float s = 0.f;
    #pragma unroll
    for (int t = 0; t < 8; ++t) {
      #pragma unroll
      for (int r = 0; r < 4; ++r) sc[t][r] = exp2f((sc[t][r] - m) * L2E);
      s += (sc[t][0] + sc[t][1]) + (sc[t][2] + sc[t][3]);
    }
    s += __shfl_xor(s, 16, 64);
    s += __shfl_xor(s, 32, 64);
    l = l * alpha + s;
    #pragma unroll
    for (int dt = 0; dt < 4; ++dt)
      #pragma unroll
      for (int r = 0; r < 4; ++r) o[dt][r] *= alpha;

    // P^T -> LDS in B-frag orientation: lane writes 4 contiguous kv (b64)
    #pragma unroll
    for (int t = 0; t < 8; ++t) {
      f16x4 ph;
      #pragma unroll
      for (int r = 0; r < 4; ++r) ph[r] = (_Float16)sc[t][r];
      *(f16x4*)&P[wave][l16][t * 16 + quad * 4] = ph;
    }
    asm volatile("s_waitcnt lgkmcnt(0)" ::: "memory");

    // PV: o[d][q] += V^T-frag x P^T-frag over four 32-kv k-steps
    #pragma unroll
    for (int ks = 0; ks < 4; ++ks) {
      if (kv0 + ks * 32 < kvend) {
        f16x8 pf = *(const f16x8*)&P[wave][l16][ks * 32 + quad * 8];
        #pragma unroll
        for (int dt = 0; dt < 4; ++dt) {
          f16x8 vf = *(const f16x8*)&vb[(size_t)(dt * 16 + l16) * 2048 + kv0 + ks * 32 + quad * 8];
          o[dt] = __builtin_amdgcn_mfma_f32_16x16x32_f16(vf, pf, o[dt], 0, 0, 0);
        }
      }
    }
  }

  // publish per-wave partials: o row = d = dt*16+quad*4+r, col = q = l16
  #pragma unroll
  for (int dt = 0; dt < 4; ++dt)
    *(f32x4*)&ob[wave][l16][dt * 16 + quad * 4] = o[dt];
  if (quad == 0) {
    mlb[wave][0][l16] = m;
    mlb[wave][1][l16] = l;
  }
  __syncthreads();

  // merge 4 splits; thread t -> row t>>4, cols (t&15)*4..+3
  {
    int row = tid >> 4;
    int c0  = (tid & 15) * 4;
    float m0 = mlb[0][0][row], m1 = mlb[1][0][row];
    float m2 = mlb[2][0][row], m3 = mlb[3][0][row];
    float M  = fmaxf(fmaxf(m0, m1), fmaxf(m2, m3));
    float w0 = exp2f((m0 - M) * L2E), w1 = exp2f((m1 - M) * L2E);
    float w2 = exp2f((m2 - M) * L2E), w3 = exp2f((m3 - M) * L2E);
    float L  = w0 * mlb[0][1][row] + w1 * mlb[1][1][row]
             + w2 * mlb[2][1][row] + w3 * mlb[3][1][row];
    float inv = 1.0f / (L * 32.0f);            // sqrt(H)=32 applied AFTER softmax
    f32x4 res;
    #pragma unroll
    for (int j = 0; j < 4; ++j)
      res[j] = (w0 * ob[0][row][c0 + j] + w1 * ob[1][row][c0 + j]
              + w2 * ob[2][row][c0 + j] + w3 * ob[3][row][c0 + j]) * inv;
    *(f32x4*)&out[((size_t)b * 2048 + q0 + row) * 64 + c0] = res;
  }
}

// ---------------------------------------------------------------------------
extern "C" void kernel_launch(void* const* d_in, const int* in_sizes, int n_in,
                              void* d_out, int out_size, void* d_ws, size_t ws_size,
                              hipStream_t stream) {
  const float* x  = (const float*)d_in[0];
  const float* Wq = (const float*)d_in[1];
  const float* bq = (const float*)d_in[2];
  const float* Wk = (const float*)d_in[3];
  const float* bk = (const float*)d_in[4];
  const float* Wv = (const float*)d_in[5];
  const float* bv = (const float*)d_in[6];
  float* out = (float*)d_out;

  // ws layout (f16): WtF 192*1024 | q 16384*64 | k 16384*64 | vt 8*64*2048 (~6.7MB)
  _Float16* WtF = (_Float16*)d_ws;
  _Float16* qo  = WtF + 192 * 1024;
  _Float16* ko  = qo + 16384 * 64;
  _Float16* vt  = ko + 16384 * 64;

  hipLaunchKernelGGL(wt_prep,  dim3(48),   dim3(256), 0, stream, Wq, Wk, Wv, WtF);
  hipLaunchKernelGGL(qkv_gemm, dim3(512),  dim3(512), 0, stream, x, WtF, bq, bk, bv, qo, ko, vt);
  hipLaunchKernelGGL(attn,     dim3(1024), dim3(256), 0, stream, qo, ko, vt, out);
}

// Round 2
// 151.577 us; speedup vs baseline: 1.0334x; 1.0252x over previous
//
#include <hip/hip_runtime.h>

// Problem: B=8, S=2048, H=1024, D=64. fp32 in, fp32 out.
// out = softmax_causal(q k^T) / sqrt(H) @ v   (softmax FIRST, then /32)

typedef float     f32x4 __attribute__((ext_vector_type(4)));
typedef _Float16  f16x8 __attribute__((ext_vector_type(8)));
typedef _Float16  f16x4 __attribute__((ext_vector_type(4)));

// ---------------------------------------------------------------------------
// Kernel 1: pack W{q,k,v} into MFMA B-fragment order (f16) via LDS transpose.
// Frag f = (kstep*12 + nt)*64 + lane holds 8 f16:
//   element j = W[n = nt*16 + (lane&15)][k = kstep*32 + (lane>>4)*8 + j]
// Grid 48 = 3 W x 16 k-tiles of 64. Coalesced f32x4 reads; frag-ordered writes.
__global__ __launch_bounds__(256) void wt_prep(const float* __restrict__ Wq,
                                               const float* __restrict__ Wk,
                                               const float* __restrict__ Wv,
                                               _Float16* __restrict__ WtF) {
  const int w  = blockIdx.x >> 4;              // which W
  const int kt = blockIdx.x & 15;              // k-tile of 64
  const float* src = (w == 0) ? Wq : (w == 1 ? Wk : Wv);
  __shared__ _Float16 ls[64][72];              // [local k][n], padded
  const int t = threadIdx.x;
  {
    int rr = t >> 4;                           // 0..15
    int c4 = (t & 15) * 4;
    #pragma unroll
    for (int ri = 0; ri < 4; ++ri) {
      int k = rr + ri * 16;                    // local k 0..63
      f32x4 f = *(const f32x4*)&src[(size_t)(kt * 64 + k) * 64 + c4];
      #pragma unroll
      for (int j = 0; j < 4; ++j) ls[k][c4 + j] = (_Float16)f[j];
    }
  }
  __syncthreads();
  const int lane = t & 63, l16 = lane & 15, quad = lane >> 4;
  #pragma unroll
  for (int h = 0; h < 2; ++h) {
    int fid     = h * 4 + (t >> 6);            // 0..7
    int kstep_l = fid >> 2;                    // 0..1
    int ntl     = fid & 3;                     // 0..3
    int nt      = w * 4 + ntl;
    int kstep   = kt * 2 + kstep_l;
    f16x8 o;
    #pragma unroll
    for (int j = 0; j < 8; ++j) o[j] = ls[kstep_l * 32 + quad * 8 + j][ntl * 16 + l16];
    *(f16x8*)&WtF[((size_t)(kstep * 12 + nt) * 64 + lane) * 8] = o;
  }
}

// ---------------------------------------------------------------------------
// Kernel 2: QKV projection. Grid 512 (M-tile=32), 512 threads (8 waves),
// 2 blocks/CU -> 16 waves/CU. Whole 32x1024 x-tile staged ONCE into a 64KB
// XOR-swizzled LDS buffer (granule=8 f16; phys_g = g ^ (row&7) -> conflict-free
// staging writes AND A-frag ds_read_b128). Single barrier; then each wave
// independently streams 96 coalesced B-frag loads + 96 MFMAs.
// Wave split: mhalf = wave>>2 (16 rows), ngrp = wave&3 (3 n-tiles).
__global__ __launch_bounds__(512, 4) void qkv_gemm(const float* __restrict__ x,
                                                   const _Float16* __restrict__ WtF,
                                                   const float* __restrict__ bq,
                                                   const float* __restrict__ bk,
                                                   const float* __restrict__ bv,
                                                   _Float16* __restrict__ qo,
                                                   _Float16* __restrict__ ko,
                                                   _Float16* __restrict__ vt) {
  __shared__ _Float16 xs[32 * 1024];           // exactly 64 KB
  const int tid  = threadIdx.x;
  const int wave = tid >> 6, lane = tid & 63;
  const int l16  = lane & 15, quad = lane >> 4;
  const int mhalf = wave >> 2;                 // 0..1
  const int ngrp  = wave & 3;                  // 0..3
  const int m0    = blockIdx.x * 32;

  // --- stage x tile (fp32 -> f16), coalesced: 16-lane groups read 256B runs
  {
    int row   = tid >> 4;                      // 0..31
    int cbase = (tid & 15) * 4;
    const float* xrow = x + (size_t)(m0 + row) * 1024;
    int key = row & 7;
    #pragma unroll
    for (int j = 0; j < 16; ++j) {
      int col = cbase + j * 64;
      f32x4 f = *(const f32x4*)&xrow[col];
      f16x4 hh;
      #pragma unroll
      for (int e = 0; e < 4; ++e) hh[e] = (_Float16)f[e];
      int g   = col >> 3;                      // granule index 0..127
      int sub = col & 7;                       // 0 or 4
      *(f16x4*)&xs[(size_t)row * 1024 + (size_t)((g ^ key) << 3) + sub] = hh;
    }
  }
  __syncthreads();

  f32x4 acc0 = (f32x4){0.f,0.f,0.f,0.f};
  f32x4 acc1 = (f32x4){0.f,0.f,0.f,0.f};
  f32x4 acc2 = (f32x4){0.f,0.f,0.f,0.f};

  const int arow = mhalf * 16 + l16;
  const _Float16* abase = xs + (size_t)arow * 1024;
  const int akey = arow & 7;
  const _Float16* wbase = WtF + ((size_t)(ngrp * 3) * 64 + lane) * 8;

  #pragma unroll 4
  for (int kstep = 0; kstep < 32; ++kstep) {
    f16x8 a = *(const f16x8*)(abase + (((kstep * 4 + quad) ^ akey) << 3));
    const _Float16* wk = wbase + (size_t)kstep * (12 * 64 * 8);
    f16x8 b0 = *(const f16x8*)(wk);
    f16x8 b1 = *(const f16x8*)(wk + 512);
    f16x8 b2 = *(const f16x8*)(wk + 1024);
    acc0 = __builtin_amdgcn_mfma_f32_16x16x32_f16(a, b0, acc0, 0, 0, 0);
    acc1 = __builtin_amdgcn_mfma_f32_16x16x32_f16(a, b1, acc1, 0, 0, 0);
    acc2 = __builtin_amdgcn_mfma_f32_16x16x32_f16(a, b2, acc2, 0, 0, 0);
  }

  // --- epilogue: C/D col=lane&15, row=quad*4+r. Bias add, f16 write.
  f32x4 accs[3] = {acc0, acc1, acc2};
  #pragma unroll
  for (int i = 0; i < 3; ++i) {
    int nt  = ngrp * 3 + i;
    int col = nt * 16 + l16;
    float bias = (nt < 4) ? bq[col] : (nt < 8) ? bk[col - 64] : bv[col - 128];
    #pragma unroll
    for (int r = 0; r < 4; ++r) {
      int m = m0 + mhalf * 16 + quad * 4 + r;  // global row = b*2048+s
      _Float16 hv = (_Float16)(accs[i][r] + bias);
      if (nt < 4)      qo[(size_t)m * 64 + col] = hv;
      else if (nt < 8) ko[(size_t)m * 64 + (col - 64)] = hv;
      else {                                   // v stored transposed: vt[b][d][s]
        int b = m >> 11, s = m & 2047;
        vt[((size_t)b * 64 + (col - 128)) * 2048 + s] = hv;
      }
    }
  }
}

// ---------------------------------------------------------------------------
// Kernel 3: causal attention, flash-style online softmax.
//
// THIS ROUND: uniform-work blocks via complementary q-tile PAIRING.
// Block (b, pair) has 512 threads / 8 waves: waves 0-3 process q-tile
// qt = pair, waves 4-7 process qt = 127-pair. Total kv per block =
// 16(pair+1) + 16(128-pair) = 2064 = CONSTANT, so no scheduler block->CU
// mapping can cluster heavy tiles onto one CU (the round-1 hypothesis for
// the 42us attn: consecutive blocks were the 8 heaviest tiles and could
// co-locate). Grid 512 x 69KB LDS -> exactly 2 blocks/CU, co-resident,
// batch-per-XCD preserved (b = blk&7). Swapped-operand MFMA layout kept:
// scores = mfma(K,Q) -> per-lane kv-row stats; PV = mfma(V^T, P^T).
__global__ __launch_bounds__(512, 4) void attn(const _Float16* __restrict__ q,
                                               const _Float16* __restrict__ k,
                                               const _Float16* __restrict__ vt,
                                               float* __restrict__ out) {
  const int blk  = blockIdx.x;
  const int pair = blk >> 3;                   // 0..63
  const int b    = blk & 7;
  const int tid  = threadIdx.x;
  const int wave = tid >> 6, lane = tid & 63;
  const int l16  = lane & 15, quad = lane >> 4;
  const int wv   = wave & 3;                   // kv-split index within tile
  const int half = wave >> 2;                  // 0: qt=pair, 1: qt=127-pair
  const int qt   = half ? (127 - pair) : pair;
  const int q0   = qt * 16;

  __shared__ _Float16 P[8][16][136];           // per-wave P^T buffer [q][kv]
  __shared__ float    ob[8][16][68];           // per-wave partial O
  __shared__ float    mlb[8][2][16];           // per-wave (m, l) per q-row

  const _Float16* qb = q  + (size_t)b * 2048 * 64;
  const _Float16* kb = k  + (size_t)b * 2048 * 64;
  const _Float16* vb = vt + (size_t)b * 64 * 2048;

  f16x8 qf0 = *(const f16x8*)&qb[(q0 + l16) * 64 + quad * 8];
  f16x8 qf1 = *(const f16x8*)&qb[(q0 + l16) * 64 + 32 + quad * 8];

  f32x4 o[4];
  #pragma unroll
  for (int i = 0; i < 4; ++i) o[i] = (f32x4){0.f, 0.f, 0.f, 0.f};
  float m = -1e30f, l = 0.f;                   // per-lane: stats for q = q0+l16
  const float L2E = 1.44269504088896340736f;
  const int qrow  = q0 + l16;
  const int kvend = q0 + 16;                   // causal: skv <= sq <= q0+15

  for (int kv0 = wv * 128; kv0 < kvend; kv0 += 512) {
    f32x4 sc[8];                               // S^T: sc[t][r] = S[kv0+t*16+quad*4+r][q0+l16]
    #pragma unroll
    for (int t = 0; t < 8; ++t) {
      int kvc = kv0 + t * 16;
      f32x4 c;
      if (kvc < kvend) {
        c = (f32x4){0.f, 0.f, 0.f, 0.f};
        f16x8 kf0 = *(const f16x8*)&kb[(kvc + l16) * 64 + quad * 8];
        f16x8 kf1 = *(const f16x8*)&kb[(kvc + l16) * 64 + 32 + quad * 8];
        c = __builtin_amdgcn_mfma_f32_16x16x32_f16(kf0, qf0, c, 0, 0, 0);
        c = __builtin_amdgcn_mfma_f32_16x16x32_f16(kf1, qf1, c, 0, 0, 0);
        if (kvc + 15 > q0) {                   // causal mask, diagonal tiles only
          #pragma unroll
          for (int r = 0; r < 4; ++r)
            if (kvc + quad * 4 + r > qrow) c[r] = -1e30f;
        }
      } else {
        c = (f32x4){-1e30f, -1e30f, -1e30f, -1e30f};
      }
      sc[t] = c;
    }

    // row max: in-register over this lane's 32 kv values, then across quads
    float mx = -1e30f;
    #pragma unroll
    for (int t = 0; t < 8; ++t)
      mx = fmaxf(mx, fmaxf(fmaxf(sc[t][0], sc[t][1]), fmaxf(sc[t][2], sc[t][3])));
    mx = fmaxf(mx, __shfl_xor(mx, 16, 64));
    mx = fmaxf(mx, __shfl_xor(mx, 32, 64));
    float mnew  = fmaxf(m, mx);
    float alpha = exp2f((m - mnew) * L2E);
    m = mnew;

    float s = 0.f;
    #pragma unroll
    for (int t = 0; t < 8; ++t) {
      #pragma unroll
      for (int r = 0; r < 4; ++r) sc[t][r] = exp2f((sc[t][r] - m) * L2E);
      s += (sc[t][0] + sc[t][1]) + (sc[t][2] + sc[t][3]);
    }
    s += __shfl_xor(s, 16, 64);
    s += __shfl_xor(s, 32, 64);
    l = l * alpha + s;
    #pragma unroll
    for (int dt = 0; dt < 4; ++dt)
      #pragma unroll
      for (int r = 0; r < 4; ++r) o[dt][r] *= alpha;

    // P^T -> LDS in B-frag orientation: lane writes 4 contiguous kv (b64)
    #pragma unroll
    for (int t = 0; t < 8; ++t) {
      f16x4 ph;
      #pragma unroll
      for (int r = 0; r < 4; ++r) ph[r] = (_Float16)sc[t][r];
      *(f16x4*)&P[wave][l16][t * 16 + quad * 4] = ph;
    }
    asm volatile("s_waitcnt lgkmcnt(0)" ::: "memory");

    // PV: o[d][q] += V^T-frag x P^T-frag over four 32-kv k-steps
    #pragma unroll
    for (int ks = 0; ks < 4; ++ks) {
      if (kv0 + ks * 32 < kvend) {
        f16x8 pf = *(const f16x8*)&P[wave][l16][ks * 32 + quad * 8];
        #pragma unroll
        for (int dt = 0; dt < 4; ++dt) {
          f16x8 vf = *(const f16x8*)&vb[(size_t)(dt * 16 + l16) * 2048 + kv0 + ks * 32 + quad * 8];
          o[dt] = __builtin_amdgcn_mfma_f32_16x16x32_f16(vf, pf, o[dt], 0, 0, 0);
        }
      }
    }
  }

  // publish per-wave partials: o row = d = dt*16+quad*4+r, col = q = l16
  #pragma unroll
  for (int dt = 0; dt < 4; ++dt)
    *(f32x4*)&ob[wave][l16][dt * 16 + quad * 4] = o[dt];
  if (quad == 0) {
    mlb[wave][0][l16] = m;
    mlb[wave][1][l16] = l;
  }
  __syncthreads();

  // merge 4 kv-splits per half; threads 0-255 -> half 0, 256-511 -> half 1.
  {
    int mhalf = tid >> 8;
    int idx   = tid & 255;
    int row   = idx >> 4;
    int c0    = (idx & 15) * 4;
    int wbase = mhalf * 4;
    int qth   = mhalf ? (127 - pair) : pair;
    float m0 = mlb[wbase + 0][0][row], m1 = mlb[wbase + 1][0][row];
    float m2 = mlb[wbase + 2][0][row], m3 = mlb[wbase + 3][0][row];
    float M  = fmaxf(fmaxf(m0, m1), fmaxf(m2, m3));
    float w0 = exp2f((m0 - M) * L2E), w1 = exp2f((m1 - M) * L2E);
    float w2 = exp2f((m2 - M) * L2E), w3 = exp2f((m3 - M) * L2E);
    float L  = w0 * mlb[wbase + 0][1][row] + w1 * mlb[wbase + 1][1][row]
             + w2 * mlb[wbase + 2][1][row] + w3 * mlb[wbase + 3][1][row];
    float inv = 1.0f / (L * 32.0f);            // sqrt(H)=32 applied AFTER softmax
    f32x4 res;
    #pragma unroll
    for (int j = 0; j < 4; ++j)
      res[j] = (w0 * ob[wbase + 0][row][c0 + j] + w1 * ob[wbase + 1][row][c0 + j]
              + w2 * ob[wbase + 2][row][c0 + j] + w3 * ob[wbase + 3][row][c0 + j]) * inv;
    *(f32x4*)&out[((size_t)b * 2048 + qth * 16 + row) * 64 + c0] = res;
  }
}

// ---------------------------------------------------------------------------
extern "C" void kernel_launch(void* const* d_in, const int* in_sizes, int n_in,
                              void* d_out, int out_size, void* d_ws, size_t ws_size,
                              hipStream_t stream) {
  const float* x  = (const float*)d_in[0];
  const float* Wq = (const float*)d_in[1];
  const float* bq = (const float*)d_in[2];
  const float* Wk = (const float*)d_in[3];
  const float* bk = (const float*)d_in[4];
  const float* Wv = (const float*)d_in[5];
  const float* bv = (const float*)d_in[6];
  float* out = (float*)d_out;

  // ws layout (f16): WtF 192*1024 | q 16384*64 | k 16384*64 | vt 8*64*2048 (~6.7MB)
  _Float16* WtF = (_Float16*)d_ws;
  _Float16* qo  = WtF + 192 * 1024;
  _Float16* ko  = qo + 16384 * 64;
  _Float16* vt  = ko + 16384 * 64;

  hipLaunchKernelGGL(wt_prep,  dim3(48),  dim3(256), 0, stream, Wq, Wk, Wv, WtF);
  hipLaunchKernelGGL(qkv_gemm, dim3(512), dim3(512), 0, stream, x, WtF, bq, bk, bv, qo, ko, vt);
  hipLaunchKernelGGL(attn,     dim3(512), dim3(512), 0, stream, qo, ko, vt, out);
}